// Round 7
// baseline (655.410 us; speedup 1.0000x reference)
//
#include <hip/hip_runtime.h>
#include <hip/hip_cooperative_groups.h>

namespace cg = cooperative_groups;

#define NB    128
#define P     512
#define PP    262144            // P*P
#define TOT   33554432          // NB*PP
#define MAX_IT 100

// d_ws layout (float offsets); ws >= 1.6GB per poison-fill evidence
#define WS_W     0              // 262144 : |1/(s.s^T)+1e-5|
#define WS_U     262144         // 65536
#define WS_V     327680         // 65536
#define WS_CP    393216         // 2 * 524288 : col partials (sink_c: [buf][n][8][512])
#define WS_ERRP  1441792        // 2 * 1024
#define WS_DONE  1443840        // flag

typedef float f32x2 __attribute__((ext_vector_type(2)));

__device__ __forceinline__ f32x2 pkfma(f32x2 a, f32x2 b, f32x2 c) {
  f32x2 d;
  asm("v_pk_fma_f32 %0, %1, %2, %3" : "=v"(d) : "v"(a), "v"(b), "v"(c));
  return d;
}

__device__ __forceinline__ float bfbits(unsigned u) {
  union { unsigned b; float f; } x; x.b = u; return x.f;
}

__global__ void prep_kernel(const float* __restrict__ species,
                            float* __restrict__ ws, float* __restrict__ cost) {
  int tid = blockIdx.x * 256 + threadIdx.x;      // grid covers PP
  if (tid < PP) {
    int i = tid >> 9, j = tid & (P - 1);
    const float* si = species + i * 8;
    const float* sj = species + j * 8;
    float g = 0.f;
#pragma unroll
    for (int k = 0; k < 8; ++k) g += si[k] * sj[k];
    ws[WS_W + tid] = fabsf(1.0f / g + 1e-5f);
  }
  if (tid < NB * P) ws[WS_U + tid] = 0.f;
  if (tid < NB) cost[tid] = 0.f;
  if (tid == 0) ws[WS_DONE] = 0.f;
}

// writes C and dist in full; 4 elems/thread
__global__ void cmat_kernel(const float* __restrict__ x, const float* __restrict__ y,
                            const float* __restrict__ W,
                            float* __restrict__ C, float* __restrict__ dist) {
  int g = blockIdx.x * 256 + threadIdx.x;        // [0, TOT/4)
  int base = g << 2;
  int n = base >> 18;
  int r = base & (PP - 1);
  int i = r >> 9, j0 = r & (P - 1);
  const float* xp = x + ((n << 9) + i) * 3;
  float x0 = xp[0], x1 = xp[1], x2 = xp[2];
  const float* yp = y + ((n << 9) + j0) * 3;
  float4 w4 = *reinterpret_cast<const float4*>(W + r);
  float wv[4] = { w4.x, w4.y, w4.z, w4.w };
  float c[4], d[4];
#pragma unroll
  for (int q = 0; q < 4; ++q) {
    float dx = x0 - yp[q * 3 + 0];
    float dy = x1 - yp[q * 3 + 1];
    float dz = x2 - yp[q * 3 + 2];
    dx = rintf(dx) - dx; dy = rintf(dy) - dy; dz = rintf(dz) - dz;
    float ds = dx * dx + dy * dy + dz * dz;
    d[q] = ds;
    c[q] = ds * wv[q];
  }
  *reinterpret_cast<float4*>(C + base)    = make_float4(c[0], c[1], c[2], c[3]);
  *reinterpret_cast<float4*>(dist + base) = make_float4(d[0], d[1], d[2], d[3]);
}

// ---- FAST: 1024 blocks x 256 threads (4 blocks/CU @ <=128 VGPR), kreg[64]:
// 16 rows x 8 strided cols per thread, bf16-packed -> ~110 VGPR, NO SPILL.
__global__ __launch_bounds__(256, 4)
void sink_c(const float* __restrict__ x, const float* __restrict__ y,
            float* __restrict__ ws) {
  cg::grid_group grid = cg::this_grid();
  const int tid  = threadIdx.x;
  const int lane = tid & 63;
  const int wid  = tid >> 6;               // 0..3
  const int bid  = blockIdx.x;             // 0..1023
  const int n    = bid >> 3;               // batch
  const int e8   = bid & 7;                // eighth-batch: 64 rows

  float* u    = ws + WS_U;
  float* cp   = ws + WS_CP;
  float* errP = ws + WS_ERRP;

  __shared__ float ys[P * 3];
  __shared__ float vLDS[P];
  __shared__ float cbuf[4][P];
  __shared__ float wdu[4];
  __shared__ float ebc;

  {
    const float* yb = y + (size_t)(n << 9) * 3;
    for (int q = tid; q < P * 3; q += 256) ys[q] = yb[q];
  }
  vLDS[tid] = 0.f; vLDS[tid + 256] = 0.f;
  __syncthreads();

  // K build: rows rl = (e8<<6)+(wid<<4)+r (r=0..15), cols lane+64t (t=0..7)
  unsigned kreg[64];
#pragma unroll
  for (int r = 0; r < 16; ++r) {
    const int rl = (e8 << 6) + (wid << 4) + r;
    const float* xp = x + (size_t)((n << 9) + rl) * 3;
    const float x0 = xp[0], x1 = xp[1], x2 = xp[2];
    const float* Wr = ws + WS_W + (rl << 9) + lane;
    unsigned kk[8];
#pragma unroll
    for (int t = 0; t < 8; ++t) {
      const int j = lane + (t << 6);
      float w = Wr[t << 6];
      float dx = x0 - ys[j * 3 + 0];
      float dy = x1 - ys[j * 3 + 1];
      float dz = x2 - ys[j * 3 + 2];
      dx = rintf(dx) - dx; dy = rintf(dy) - dy; dz = rintf(dz) - dz;
      float ds = dx * dx + dy * dy + dz * dz;
      float kf = __expf(-10.f * (ds * w));
      unsigned b = __float_as_uint(kf);
      kk[t] = (b + 0x7fffu + ((b >> 16) & 1u)) >> 16;   // RNE to bf16
    }
#pragma unroll
    for (int h = 0; h < 4; ++h)
      kreg[(r << 2) + h] = kk[2 * h] | (kk[2 * h + 1] << 16);
  }

  const float logmu = logf(1.0f / 512.0f + 1e-8f);
  const float muv   = 1.0f / 512.0f + 1e-8f;

  for (int it = 0; it < MAX_IT; ++it) {
    const int buf = it & 1;
    f32x2 ev2[4], ca2[4];
#pragma unroll
    for (int h = 0; h < 4; ++h) {
      ev2[h].x = __expf(10.f * vLDS[lane + ((2 * h) << 6)]);
      ev2[h].y = __expf(10.f * vLDS[lane + ((2 * h + 1) << 6)]);
      ca2[h].x = 0.f; ca2[h].y = 0.f;
    }

    float du = 0.f;
#pragma unroll
    for (int r = 0; r < 16; ++r) {
      f32x2 k2[4];
#pragma unroll
      for (int h = 0; h < 4; ++h) {
        unsigned kw = kreg[(r << 2) + h];
        k2[h].x = bfbits(kw << 16);
        k2[h].y = bfbits(kw & 0xffff0000u);
      }
      f32x2 s2 = {0.f, 0.f};
      s2 = pkfma(k2[0], ev2[0], s2);
      s2 = pkfma(k2[1], ev2[1], s2);
      s2 = pkfma(k2[2], ev2[2], s2);
      s2 = pkfma(k2[3], ev2[3], s2);
      float s = s2.x + s2.y;
#pragma unroll
      for (int o = 32; o > 0; o >>= 1) s += __shfl_xor(s, o);
      const int rowg = (n << 9) + (e8 << 6) + (wid << 4) + r;
      float uo = u[rowg];
      float un = 0.1f * (logmu - __logf(s));
      du += fabsf(un - uo);
      if (lane == 0) u[rowg] = un;
      float eu = __fdividef(muv, s);       // = exp(10*un), runtime-proven (R6)
      f32x2 eu2 = { eu, eu };
      ca2[0] = pkfma(k2[0], eu2, ca2[0]);
      ca2[1] = pkfma(k2[1], eu2, ca2[1]);
      ca2[2] = pkfma(k2[2], eu2, ca2[2]);
      ca2[3] = pkfma(k2[3], eu2, ca2[3]);
    }
#pragma unroll
    for (int h = 0; h < 4; ++h) {
      cbuf[wid][lane + ((2 * h) << 6)]     = ca2[h].x;
      cbuf[wid][lane + ((2 * h + 1) << 6)] = ca2[h].y;
    }
    if (lane == 0) wdu[wid] = du;
    __syncthreads();

    {
      float s1 = cbuf[0][tid] + cbuf[1][tid] + cbuf[2][tid] + cbuf[3][tid];
      int c2 = tid + 256;
      float s2 = cbuf[0][c2] + cbuf[1][c2] + cbuf[2][c2] + cbuf[3][c2];
      float* cpd = cp + buf * 524288 + (n << 12) + (e8 << 9);
      cpd[tid] = s1; cpd[c2] = s2;
      if (tid == 0) errP[(buf << 10) + bid] = wdu[0] + wdu[1] + wdu[2] + wdu[3];
    }
    grid.sync();

    {
      const float* cpb = cp + buf * 524288 + (n << 12);
      float sc1 = 0.f, sc2 = 0.f;
      int c2 = tid + 256;
#pragma unroll
      for (int e = 0; e < 8; ++e) {
        sc1 += cpb[(e << 9) + tid];
        sc2 += cpb[(e << 9) + c2];
      }
      vLDS[tid] = 0.1f * (logmu - __logf(sc1));
      vLDS[c2]  = 0.1f * (logmu - __logf(sc2));
    }
    if (wid == 0) {
      float e = 0.f;
#pragma unroll
      for (int q = 0; q < 16; ++q) e += errP[(buf << 10) + lane + (q << 6)];
#pragma unroll
      for (int o = 32; o > 0; o >>= 1) e += __shfl_xor(e, o);
      if (lane == 0) ebc = e;
    }
    __syncthreads();
    if (ebc < 12.8f) break;                // errTot/128 < 0.1, update applied
  }

  if (e8 == 0) {
    ws[WS_V + (n << 9) + tid]       = vLDS[tid];
    ws[WS_V + (n << 9) + tid + 256] = vLDS[tid + 256];
  }
  if (tid == 0) ws[WS_DONE] = 1.0f;
}

// ---- RESCUE: proven envelope (512x512, low VGPR), K = exp(-10*C) from f32 C.
// Runs only if sink_c never executed (DONE flag).
__global__ __launch_bounds__(512, 4)
void sink_rescue(const float* __restrict__ Cm, float* __restrict__ ws) {
  if (ws[WS_DONE] != 0.f) return;          // uniform early exit
  cg::grid_group grid = cg::this_grid();
  float* u    = ws + WS_U;
  float* cp   = ws + WS_CP;
  float* errP = ws + WS_ERRP;

  const int tid  = threadIdx.x;
  const int lane = tid & 63;
  const int wid  = tid >> 6;
  const int bid  = blockIdx.x;
  const int n    = bid >> 2;
  const int rb   = bid & 3;
  const int row0 = (n << 9) + (rb << 7);

  __shared__ float vLDS[P];
  __shared__ float colsum[P];
  __shared__ float red[P];
  __shared__ float wdu[8];

  vLDS[tid] = 0.f;
  __syncthreads();

  const float logmu = logf(1.0f / 512.0f + 1e-8f);

  for (int it = 0; it < MAX_IT; ++it) {
    const int buf = it & 1;
    float ev[8], colacc[8];
#pragma unroll
    for (int t = 0; t < 8; ++t) {
      ev[t] = __expf(10.f * vLDS[(lane << 3) + t]);
      colacc[t] = 0.f;
    }
    colsum[tid] = 0.f;
    __syncthreads();

    float myDu = 0.f;
#pragma unroll 2
    for (int r = 0; r < 16; ++r) {
      int row = row0 + (wid << 4) + r;
      const float* Cr = Cm + ((size_t)row << 9) + (lane << 3);
      float4 ca = *reinterpret_cast<const float4*>(Cr);
      float4 cb = *reinterpret_cast<const float4*>(Cr + 4);
      float k[8];
      k[0] = __expf(-10.f * ca.x); k[1] = __expf(-10.f * ca.y);
      k[2] = __expf(-10.f * ca.z); k[3] = __expf(-10.f * ca.w);
      k[4] = __expf(-10.f * cb.x); k[5] = __expf(-10.f * cb.y);
      k[6] = __expf(-10.f * cb.z); k[7] = __expf(-10.f * cb.w);
      float s = 0.f;
#pragma unroll
      for (int t = 0; t < 8; ++t) s = fmaf(k[t], ev[t], s);
#pragma unroll
      for (int o = 32; o > 0; o >>= 1) s += __shfl_xor(s, o);
      float uo = u[row];
      float un = 0.1f * (logmu - __logf(s));
      myDu += fabsf(un - uo);
      if (lane == 0) u[row] = un;
      float eu = __expf(10.f * un);
#pragma unroll
      for (int t = 0; t < 8; ++t) colacc[t] = fmaf(k[t], eu, colacc[t]);
    }
#pragma unroll
    for (int t = 0; t < 8; ++t) atomicAdd(&colsum[(lane << 3) + t], colacc[t]);
    if (lane == 0) wdu[wid] = myDu;
    __syncthreads();

    cp[(buf << 18) + (n << 11) + (rb << 9) + tid] = colsum[tid];
    if (tid == 0) {
      errP[(buf << 9) + bid] = wdu[0] + wdu[1] + wdu[2] + wdu[3]
                             + wdu[4] + wdu[5] + wdu[6] + wdu[7];
    }
    grid.sync();

    const float* cpb = cp + (buf << 18) + (n << 11);
    float sc = cpb[tid] + cpb[512 + tid] + cpb[1024 + tid] + cpb[1536 + tid];
    float vc = 0.1f * (logmu - __logf(sc));

    red[tid] = errP[(buf << 9) + tid];
    __syncthreads();
#pragma unroll
    for (int o = 256; o > 0; o >>= 1) {
      if (tid < o) red[tid] += red[tid + o];
      __syncthreads();
    }
    float errTot = red[0];
    vLDS[tid] = vc;
    __syncthreads();
    if (errTot < 12.8f) break;
  }

  if (rb == 0) ws[WS_V + (n << 9) + tid] = vLDS[tid];
}

// pi = exp((u_i + v_j - C)/eps), cost[n] += pi*C; C recomputed on the fly
__global__ __launch_bounds__(256)
void pi_kernel(const float* __restrict__ x, const float* __restrict__ y,
               const float* __restrict__ ws,
               float* __restrict__ pi, float* __restrict__ cost) {
  const int tid  = threadIdx.x;
  const int lane = tid & 63;
  const int wid  = tid >> 6;
  const int rowg = blockIdx.x * 4 + wid;
  const int n    = rowg >> 9;
  const int i    = rowg & (P - 1);

  __shared__ float ys[P * 3];
  {
    const float* yb = y + (size_t)(n << 9) * 3;
    for (int q = tid; q < P * 3; q += 256) ys[q] = yb[q];
  }
  __syncthreads();

  const int c0 = lane << 3;
  const float* xp = x + (size_t)rowg * 3;
  const float x0 = xp[0], x1 = xp[1], x2 = xp[2];
  const float uu = ws[WS_U + rowg];
  const float* vp = ws + WS_V + (n << 9) + c0;
  const float* Wr = ws + WS_W + i * P + c0;

  float acc = 0.f;
  float4 po[2];
#pragma unroll
  for (int h = 0; h < 2; ++h) {
    float4 v4 = *reinterpret_cast<const float4*>(vp + h * 4);
    float4 w4 = *reinterpret_cast<const float4*>(Wr + h * 4);
    float vv[4] = { v4.x, v4.y, v4.z, v4.w };
    float wv[4] = { w4.x, w4.y, w4.z, w4.w };
    float pq[4];
#pragma unroll
    for (int q = 0; q < 4; ++q) {
      const int j = c0 + h * 4 + q;
      float dx = x0 - ys[j * 3 + 0];
      float dy = x1 - ys[j * 3 + 1];
      float dz = x2 - ys[j * 3 + 2];
      dx = rintf(dx) - dx; dy = rintf(dy) - dy; dz = rintf(dz) - dz;
      float ds = dx * dx + dy * dy + dz * dz;
      float c  = ds * wv[q];
      float p  = __expf((uu + vv[q] - c) * 10.f);
      pq[q] = p;
      acc = fmaf(p, c, acc);
    }
    po[h] = make_float4(pq[0], pq[1], pq[2], pq[3]);
  }
  float* Pr = pi + ((size_t)rowg << 9) + c0;
  *reinterpret_cast<float4*>(Pr)     = po[0];
  *reinterpret_cast<float4*>(Pr + 4) = po[1];

#pragma unroll
  for (int o = 32; o > 0; o >>= 1) acc += __shfl_xor(acc, o);
  __shared__ float wsum[4];
  if (lane == 0) wsum[wid] = acc;
  __syncthreads();
  if (tid == 0) atomicAdd(cost + n, wsum[0] + wsum[1] + wsum[2] + wsum[3]);
}

extern "C" void kernel_launch(void* const* d_in, const int* in_sizes, int n_in,
                              void* d_out, int out_size, void* d_ws, size_t ws_size,
                              hipStream_t stream) {
  const float* x = (const float*)d_in[0];
  const float* y = (const float*)d_in[1];
  const float* species = (const float*)d_in[2];

  float* out  = (float*)d_out;
  float* cost = out;                     // 128
  float* pi   = out + 128;               // TOT
  float* C    = pi + (size_t)TOT;        // TOT
  float* dist = C + (size_t)TOT;         // TOT
  float* ws   = (float*)d_ws;

  hipLaunchKernelGGL(prep_kernel, dim3(PP / 256), dim3(256), 0, stream,
                     species, ws, cost);
  hipLaunchKernelGGL(cmat_kernel, dim3(TOT / 4 / 256), dim3(256), 0, stream,
                     x, y, ws + WS_W, C, dist);

  void* fargs[] = { (void*)&x, (void*)&y, (void*)&ws };
  hipLaunchCooperativeKernel((void*)sink_c, dim3(1024), dim3(256),
                             fargs, 0, stream);

  void* rargs[] = { (void*)&C, (void*)&ws };
  hipLaunchCooperativeKernel((void*)sink_rescue, dim3(512), dim3(512),
                             rargs, 0, stream);

  hipLaunchKernelGGL(pi_kernel, dim3(NB * P / 4), dim3(256), 0, stream,
                     x, y, ws, pi, cost);
}

// Round 8
// 416.159 us; speedup vs baseline: 1.5749x; 1.5749x over previous
//
#include <hip/hip_runtime.h>
#include <hip/hip_cooperative_groups.h>

namespace cg = cooperative_groups;

#define NB    128
#define P     512
#define PP    262144            // P*P
#define TOT   33554432          // NB*PP
#define MAX_IT 100

// d_ws layout (float offsets); ws >= 1.6GB per poison-fill evidence
#define WS_W     0              // 262144 : |1/(s.s^T)+1e-5|
#define WS_U     262144         // 65536
#define WS_V     327680         // 65536
#define WS_CP    393216         // 2 * 262144 col partials [buf][n][rb][512]
#define WS_ERRP  917504         // 2 * 512
#define WS_DONE  918528         // flag
#define WS_K     919552         // bf16[TOT] = 16777216 float slots

__device__ __forceinline__ float bfbits(unsigned u) {
  union { unsigned b; float f; } x; x.b = u; return x.f;
}

__global__ void prep_kernel(const float* __restrict__ species,
                            float* __restrict__ ws, float* __restrict__ cost) {
  int tid = blockIdx.x * 256 + threadIdx.x;      // grid covers PP
  if (tid < PP) {
    int i = tid >> 9, j = tid & (P - 1);
    const float* si = species + i * 8;
    const float* sj = species + j * 8;
    float g = 0.f;
#pragma unroll
    for (int k = 0; k < 8; ++k) g += si[k] * sj[k];
    ws[WS_W + tid] = fabsf(1.0f / g + 1e-5f);
  }
  if (tid < NB * P) ws[WS_U + tid] = 0.f;
  if (tid < NB) cost[tid] = 0.f;
  if (tid == 0) ws[WS_DONE] = 0.f;
}

// writes C (f32), dist (f32), K (bf16-packed); 4 elems/thread
__global__ void cmat_kernel(const float* __restrict__ x, const float* __restrict__ y,
                            const float* __restrict__ W,
                            float* __restrict__ C, float* __restrict__ dist,
                            unsigned short* __restrict__ K) {
  int g = blockIdx.x * 256 + threadIdx.x;        // [0, TOT/4)
  int base = g << 2;
  int n = base >> 18;
  int r = base & (PP - 1);
  int i = r >> 9, j0 = r & (P - 1);
  const float* xp = x + ((n << 9) + i) * 3;
  float x0 = xp[0], x1 = xp[1], x2 = xp[2];
  const float* yp = y + ((n << 9) + j0) * 3;
  float4 w4 = *reinterpret_cast<const float4*>(W + r);
  float wv[4] = { w4.x, w4.y, w4.z, w4.w };
  float c[4], d[4];
  unsigned kk[4];
#pragma unroll
  for (int q = 0; q < 4; ++q) {
    float dx = x0 - yp[q * 3 + 0];
    float dy = x1 - yp[q * 3 + 1];
    float dz = x2 - yp[q * 3 + 2];
    dx = rintf(dx) - dx; dy = rintf(dy) - dy; dz = rintf(dz) - dz;
    float ds = dx * dx + dy * dy + dz * dz;
    d[q] = ds;
    c[q] = ds * wv[q];
    float kf = __expf(-10.f * c[q]);
    unsigned b = __float_as_uint(kf);
    kk[q] = (b + 0x7fffu + ((b >> 16) & 1u)) >> 16;   // RNE to bf16
  }
  *reinterpret_cast<float4*>(C + base)    = make_float4(c[0], c[1], c[2], c[3]);
  *reinterpret_cast<float4*>(dist + base) = make_float4(d[0], d[1], d[2], d[3]);
  uint2 kp;
  kp.x = kk[0] | (kk[1] << 16);
  kp.y = kk[2] | (kk[3] << 16);
  *reinterpret_cast<uint2*>(K + base) = kp;
}

// ---- PRIMARY: memory-K sinkhorn (R2-proven structure, ~2.2us/iter L3-bound).
// 512 blocks x 512 threads, low VGPR, nothing big live across grid.sync.
// Block b: batch n=b>>2, row-block rb=b&3 (128 rows, 16 per wave).
__global__ __launch_bounds__(512, 4)
void sink_m(float* __restrict__ ws) {
  cg::grid_group grid = cg::this_grid();
  const unsigned short* Kus = (const unsigned short*)(ws + WS_K);
  float* u    = ws + WS_U;
  float* cp   = ws + WS_CP;
  float* errP = ws + WS_ERRP;

  const int tid  = threadIdx.x;
  const int lane = tid & 63;
  const int wid  = tid >> 6;               // 0..7
  const int bid  = blockIdx.x;
  const int n    = bid >> 2;
  const int rb   = bid & 3;
  const int row0 = (n << 9) + (rb << 7);

  __shared__ float vLDS[P];
  __shared__ float cbuf[8][P];             // per-wave column partials (no atomics)
  __shared__ float wdu[8];
  __shared__ float ebc;

  vLDS[tid] = 0.f;
  __syncthreads();

  const float logmu = logf(1.0f / 512.0f + 1e-8f);
  const float muv   = 1.0f / 512.0f + 1e-8f;

  for (int it = 0; it < MAX_IT; ++it) {
    const int buf = it & 1;
    float ev[8], colacc[8];
#pragma unroll
    for (int t = 0; t < 8; ++t) {
      ev[t] = __expf(10.f * vLDS[(lane << 3) + t]);
      colacc[t] = 0.f;
    }

    float du = 0.f;
#pragma unroll 2
    for (int r = 0; r < 16; ++r) {
      const int row = row0 + (wid << 4) + r;
      const uint4* kp = reinterpret_cast<const uint4*>(Kus + ((size_t)row << 9) + (lane << 3));
      uint4 kw = *kp;
      float k[8];
      k[0] = bfbits(kw.x << 16); k[1] = bfbits(kw.x & 0xffff0000u);
      k[2] = bfbits(kw.y << 16); k[3] = bfbits(kw.y & 0xffff0000u);
      k[4] = bfbits(kw.z << 16); k[5] = bfbits(kw.z & 0xffff0000u);
      k[6] = bfbits(kw.w << 16); k[7] = bfbits(kw.w & 0xffff0000u);
      float sA = k[0] * ev[0], sB = k[1] * ev[1];
      sA = fmaf(k[2], ev[2], sA); sB = fmaf(k[3], ev[3], sB);
      sA = fmaf(k[4], ev[4], sA); sB = fmaf(k[5], ev[5], sB);
      sA = fmaf(k[6], ev[6], sA); sB = fmaf(k[7], ev[7], sB);
      float s = sA + sB;
#pragma unroll
      for (int o = 32; o > 0; o >>= 1) s += __shfl_xor(s, o);
      float uo = u[row];
      float un = 0.1f * (logmu - __logf(s));
      du += fabsf(un - uo);
      if (lane == 0) u[row] = un;
      float eu = __fdividef(muv, s);       // = exp(10*un), runtime-proven R6/R7
#pragma unroll
      for (int t = 0; t < 8; ++t) colacc[t] = fmaf(k[t], eu, colacc[t]);
    }
#pragma unroll
    for (int t = 0; t < 8; ++t) cbuf[wid][(lane << 3) + t] = colacc[t];
    if (lane == 0) wdu[wid] = du;
    __syncthreads();

    {
      float s1 = cbuf[0][tid] + cbuf[1][tid] + cbuf[2][tid] + cbuf[3][tid]
               + cbuf[4][tid] + cbuf[5][tid] + cbuf[6][tid] + cbuf[7][tid];
      cp[(buf << 18) + (n << 11) + (rb << 9) + tid] = s1;
      if (tid == 0) {
        errP[(buf << 9) + bid] = wdu[0] + wdu[1] + wdu[2] + wdu[3]
                               + wdu[4] + wdu[5] + wdu[6] + wdu[7];
      }
    }
    grid.sync();

    {
      const float* cpb = cp + (buf << 18) + (n << 11);
      float sc = cpb[tid] + cpb[512 + tid] + cpb[1024 + tid] + cpb[1536 + tid];
      vLDS[tid] = 0.1f * (logmu - __logf(sc));
    }
    if (wid == 0) {                        // single-wave global-err reduce (R7-proven)
      float e = 0.f;
#pragma unroll
      for (int q = 0; q < 8; ++q) e += errP[(buf << 9) + lane + (q << 6)];
#pragma unroll
      for (int o = 32; o > 0; o >>= 1) e += __shfl_xor(e, o);
      if (lane == 0) ebc = e;
    }
    __syncthreads();
    if (ebc < 12.8f) break;                // errTot/128 < 0.1, update applied
  }

  if (rb == 0) ws[WS_V + (n << 9) + tid] = vLDS[tid];
  if (tid == 0) ws[WS_DONE] = 1.0f;
}

// ---- RESCUE: C-based (f32), DONE-gated; only runs if sink_m never executed.
__global__ __launch_bounds__(512, 4)
void sink_rescue(const float* __restrict__ Cm, float* __restrict__ ws) {
  if (ws[WS_DONE] != 0.f) return;          // uniform early exit
  cg::grid_group grid = cg::this_grid();
  float* u    = ws + WS_U;
  float* cp   = ws + WS_CP;
  float* errP = ws + WS_ERRP;

  const int tid  = threadIdx.x;
  const int lane = tid & 63;
  const int wid  = tid >> 6;
  const int bid  = blockIdx.x;
  const int n    = bid >> 2;
  const int rb   = bid & 3;
  const int row0 = (n << 9) + (rb << 7);

  __shared__ float vLDS[P];
  __shared__ float colsum[P];
  __shared__ float red[P];
  __shared__ float wdu[8];

  vLDS[tid] = 0.f;
  __syncthreads();

  const float logmu = logf(1.0f / 512.0f + 1e-8f);

  for (int it = 0; it < MAX_IT; ++it) {
    const int buf = it & 1;
    float ev[8], colacc[8];
#pragma unroll
    for (int t = 0; t < 8; ++t) {
      ev[t] = __expf(10.f * vLDS[(lane << 3) + t]);
      colacc[t] = 0.f;
    }
    colsum[tid] = 0.f;
    __syncthreads();

    float myDu = 0.f;
#pragma unroll 2
    for (int r = 0; r < 16; ++r) {
      int row = row0 + (wid << 4) + r;
      const float* Cr = Cm + ((size_t)row << 9) + (lane << 3);
      float4 ca = *reinterpret_cast<const float4*>(Cr);
      float4 cb = *reinterpret_cast<const float4*>(Cr + 4);
      float k[8];
      k[0] = __expf(-10.f * ca.x); k[1] = __expf(-10.f * ca.y);
      k[2] = __expf(-10.f * ca.z); k[3] = __expf(-10.f * ca.w);
      k[4] = __expf(-10.f * cb.x); k[5] = __expf(-10.f * cb.y);
      k[6] = __expf(-10.f * cb.z); k[7] = __expf(-10.f * cb.w);
      float s = 0.f;
#pragma unroll
      for (int t = 0; t < 8; ++t) s = fmaf(k[t], ev[t], s);
#pragma unroll
      for (int o = 32; o > 0; o >>= 1) s += __shfl_xor(s, o);
      float uo = u[row];
      float un = 0.1f * (logmu - __logf(s));
      myDu += fabsf(un - uo);
      if (lane == 0) u[row] = un;
      float eu = __expf(10.f * un);
#pragma unroll
      for (int t = 0; t < 8; ++t) colacc[t] = fmaf(k[t], eu, colacc[t]);
    }
#pragma unroll
    for (int t = 0; t < 8; ++t) atomicAdd(&colsum[(lane << 3) + t], colacc[t]);
    if (lane == 0) wdu[wid] = myDu;
    __syncthreads();

    cp[(buf << 18) + (n << 11) + (rb << 9) + tid] = colsum[tid];
    if (tid == 0) {
      errP[(buf << 9) + bid] = wdu[0] + wdu[1] + wdu[2] + wdu[3]
                             + wdu[4] + wdu[5] + wdu[6] + wdu[7];
    }
    grid.sync();

    const float* cpb = cp + (buf << 18) + (n << 11);
    float sc = cpb[tid] + cpb[512 + tid] + cpb[1024 + tid] + cpb[1536 + tid];
    float vc = 0.1f * (logmu - __logf(sc));

    red[tid] = errP[(buf << 9) + tid];
    __syncthreads();
#pragma unroll
    for (int o = 256; o > 0; o >>= 1) {
      if (tid < o) red[tid] += red[tid + o];
      __syncthreads();
    }
    float errTot = red[0];
    vLDS[tid] = vc;
    __syncthreads();
    if (errTot < 12.8f) break;
  }

  if (rb == 0) ws[WS_V + (n << 9) + tid] = vLDS[tid];
}

// pi = exp((u_i + v_j - C)/eps), cost[n] += pi*C; C recomputed on the fly
__global__ __launch_bounds__(256)
void pi_kernel(const float* __restrict__ x, const float* __restrict__ y,
               const float* __restrict__ ws,
               float* __restrict__ pi, float* __restrict__ cost) {
  const int tid  = threadIdx.x;
  const int lane = tid & 63;
  const int wid  = tid >> 6;
  const int rowg = blockIdx.x * 4 + wid;
  const int n    = rowg >> 9;
  const int i    = rowg & (P - 1);

  __shared__ float ys[P * 3];
  {
    const float* yb = y + (size_t)(n << 9) * 3;
    for (int q = tid; q < P * 3; q += 256) ys[q] = yb[q];
  }
  __syncthreads();

  const int c0 = lane << 3;
  const float* xp = x + (size_t)rowg * 3;
  const float x0 = xp[0], x1 = xp[1], x2 = xp[2];
  const float uu = ws[WS_U + rowg];
  const float* vp = ws + WS_V + (n << 9) + c0;
  const float* Wr = ws + WS_W + i * P + c0;

  float acc = 0.f;
  float4 po[2];
#pragma unroll
  for (int h = 0; h < 2; ++h) {
    float4 v4 = *reinterpret_cast<const float4*>(vp + h * 4);
    float4 w4 = *reinterpret_cast<const float4*>(Wr + h * 4);
    float vv[4] = { v4.x, v4.y, v4.z, v4.w };
    float wv[4] = { w4.x, w4.y, w4.z, w4.w };
    float pq[4];
#pragma unroll
    for (int q = 0; q < 4; ++q) {
      const int j = c0 + h * 4 + q;
      float dx = x0 - ys[j * 3 + 0];
      float dy = x1 - ys[j * 3 + 1];
      float dz = x2 - ys[j * 3 + 2];
      dx = rintf(dx) - dx; dy = rintf(dy) - dy; dz = rintf(dz) - dz;
      float ds = dx * dx + dy * dy + dz * dz;
      float c  = ds * wv[q];
      float p  = __expf((uu + vv[q] - c) * 10.f);
      pq[q] = p;
      acc = fmaf(p, c, acc);
    }
    po[h] = make_float4(pq[0], pq[1], pq[2], pq[3]);
  }
  float* Pr = pi + ((size_t)rowg << 9) + c0;
  *reinterpret_cast<float4*>(Pr)     = po[0];
  *reinterpret_cast<float4*>(Pr + 4) = po[1];

#pragma unroll
  for (int o = 32; o > 0; o >>= 1) acc += __shfl_xor(acc, o);
  __shared__ float wsum[4];
  if (lane == 0) wsum[wid] = acc;
  __syncthreads();
  if (tid == 0) atomicAdd(cost + n, wsum[0] + wsum[1] + wsum[2] + wsum[3]);
}

extern "C" void kernel_launch(void* const* d_in, const int* in_sizes, int n_in,
                              void* d_out, int out_size, void* d_ws, size_t ws_size,
                              hipStream_t stream) {
  const float* x = (const float*)d_in[0];
  const float* y = (const float*)d_in[1];
  const float* species = (const float*)d_in[2];

  float* out  = (float*)d_out;
  float* cost = out;                     // 128
  float* pi   = out + 128;               // TOT
  float* C    = pi + (size_t)TOT;        // TOT
  float* dist = C + (size_t)TOT;         // TOT
  float* ws   = (float*)d_ws;

  hipLaunchKernelGGL(prep_kernel, dim3(PP / 256), dim3(256), 0, stream,
                     species, ws, cost);
  hipLaunchKernelGGL(cmat_kernel, dim3(TOT / 4 / 256), dim3(256), 0, stream,
                     x, y, ws + WS_W, C, dist, (unsigned short*)(ws + WS_K));

  void* margs[] = { (void*)&ws };
  hipLaunchCooperativeKernel((void*)sink_m, dim3(512), dim3(512),
                             margs, 0, stream);

  void* rargs[] = { (void*)&C, (void*)&ws };
  hipLaunchCooperativeKernel((void*)sink_rescue, dim3(512), dim3(512),
                             rargs, 0, stream);

  hipLaunchKernelGGL(pi_kernel, dim3(NB * P / 4), dim3(256), 0, stream,
                     x, y, ws, pi, cost);
}